// Round 7
// baseline (661.829 us; speedup 1.0000x reference)
//
#include <hip/hip_runtime.h>

#define E_CONST 3
#define T_CONST 100
#define C10 10.0f
#define ALPHA_C 0.05f

__device__ inline int waveInclScan(int v, int lane) {
    #pragma unroll
    for (int off = 1; off < 64; off <<= 1) {
        int n = __shfl_up(v, off, 64);
        if (lane >= off) v += n;
    }
    return v;
}

// ---------------------------------------------------------------------------
// prep: one thread per (i,s) row. Register cumsum over T=100 via float4 row
// loads; transposed coalesced stores to cumT[i][tau][s]. Writes tlA (used by
// the fallback path only) and zero-inits acc/cnt for pair2's finalize.
// ---------------------------------------------------------------------------
__global__ __launch_bounds__(256) void prep_kernel(
    const float* __restrict__ event_out, const int* __restrict__ et,
    const int* __restrict__ labs, float* __restrict__ cumT,
    int* __restrict__ tlA, float* __restrict__ acc,
    unsigned int* __restrict__ cnt, int S)
{
    const int gid = blockIdx.x * 256 + threadIdx.x;   // 0 .. E*S-1
    if (gid == 0) { acc[0] = 0.f; cnt[0] = 0u; }
    if (gid >= E_CONST * S) return;
    const int i = gid / S;
    const int s = gid - i * S;
    const float4* __restrict__ row =
        reinterpret_cast<const float4*>(event_out + (size_t)gid * T_CONST);
    float* __restrict__ base = cumT + (size_t)i * T_CONST * S + s;

    float run = 0.f;
    #pragma unroll
    for (int c = 0; c < T_CONST / 4; ++c) {
        const float4 v = row[c];
        const float c0 = run + v.x;
        const float c1 = c0 + v.y;
        const float c2 = c1 + v.z;
        const float c3 = c2 + v.w;
        base[(size_t)(4 * c + 0) * S] = c0;
        base[(size_t)(4 * c + 1) * S] = c1;
        base[(size_t)(4 * c + 2) * S] = c2;
        base[(size_t)(4 * c + 3) * S] = c3;
        run = c3;
    }
    const int t   = et[s * E_CONST + i];
    const int lab = labs[s * E_CONST + i];
    tlA[i * S + s] = (t & 0xffff) | (lab << 16);
}

// ---------------------------------------------------------------------------
// sortmeta: one block per event. LDS histograms straight from et/labs (no
// global hist, no memset), shuffle scan, LDS-cursor counting-sort scatter.
// Emits perm (key = (t, lab1-first)), permB (lab1 sorted by t), tlP (metadata
// in perm-slot order), fstart (start of lab0 group of bin tau), b1end
// (inclusive lab1 count with t<=tau). Replaces memset+scan+scatter nodes.
// ---------------------------------------------------------------------------
__global__ __launch_bounds__(256) void sortmeta_kernel(
    const int* __restrict__ et, const int* __restrict__ labs,
    int* __restrict__ perm, int* __restrict__ permB, int* __restrict__ tlP,
    int* __restrict__ fstartA, int* __restrict__ b1endA, int S)
{
    __shared__ int histK[2 * T_CONST];
    __shared__ int histB[T_CONST];
    __shared__ int cursK[2 * T_CONST];
    __shared__ int cursB[T_CONST];
    __shared__ int wsK[4], wsB[4];
    const int i = blockIdx.x, tid = threadIdx.x;
    const int lane = tid & 63, wid = tid >> 6;

    for (int b = tid; b < 2 * T_CONST; b += 256) histK[b] = 0;
    for (int b = tid; b < T_CONST; b += 256) histB[b] = 0;
    __syncthreads();

    for (int s = tid; s < S; s += 256) {
        const int t = et[s * E_CONST + i], lab = labs[s * E_CONST + i];
        atomicAdd(&histK[t * 2 + (1 - lab)], 1);
        if (lab) atomicAdd(&histB[t], 1);
    }
    __syncthreads();

    // parallel exclusive scans (one bin per thread)
    const int vK = (tid < 2 * T_CONST) ? histK[tid] : 0;
    int inclK = waveInclScan(vK, lane);
    const int vB = (tid < T_CONST) ? histB[tid] : 0;
    int inclB = waveInclScan(vB, lane);
    if (lane == 63) { wsK[wid] = inclK; wsB[wid] = inclB; }
    __syncthreads();
    int offK = 0, offB = 0;
    for (int w = 0; w < wid; ++w) { offK += wsK[w]; offB += wsB[w]; }
    inclK += offK; inclB += offB;
    const int exclK = inclK - vK;
    const int exclB = inclB - vB;

    if (tid < 2 * T_CONST) {
        cursK[tid] = exclK;
        if (tid & 1) fstartA[i * T_CONST + (tid >> 1)] = exclK;  // bin 2t+1
    }
    if (tid < T_CONST) {
        cursB[tid] = exclB;
        b1endA[i * T_CONST + tid] = inclB;
    }
    __syncthreads();

    // scatter
    for (int s = tid; s < S; s += 256) {
        const int t = et[s * E_CONST + i], lab = labs[s * E_CONST + i];
        const int slot = atomicAdd(&cursK[t * 2 + (1 - lab)], 1);
        perm[i * S + slot] = s;
        tlP[i * S + slot]  = (t & 0xffff) | (lab << 16);
        if (lab) {
            const int sb = atomicAdd(&cursB[t], 1);
            permB[i * S + sb] = s;
        }
    }
}

// ---------------------------------------------------------------------------
// permute+exp: expF[i][tau][j] = exp(10*cumT[i][tau][perm[j]]);
//              expB[i][tau][jb] = exp(-10*cumT[i][tau][permB[jb]]), jb < n1.
// Gathers stay within one 32KB column (L1-resident); writes coalesced.
// ---------------------------------------------------------------------------
__global__ __launch_bounds__(256) void permute_kernel(
    const float* __restrict__ cumT, const int* __restrict__ perm,
    const int* __restrict__ permB, const int* __restrict__ b1endA,
    float* __restrict__ expF, float* __restrict__ expB, int S)
{
    const int colIdx = blockIdx.x;            // i*T + tau
    const int i = colIdx / T_CONST;
    const float* __restrict__ col = cumT + (size_t)colIdx * S;
    const int n1 = b1endA[i * T_CONST + T_CONST - 1];
    const int chunk = (2 * S) / 8;
    const int beg = blockIdx.y * chunk;
    const int end = beg + chunk;
    for (int idx = beg + (int)threadIdx.x; idx < end; idx += 256) {
        if (idx < S) {
            expF[(size_t)colIdx * S + idx] = __expf(C10 * col[perm[i * S + idx]]);
        } else {
            const int jb = idx - S;
            if (jb < n1)
                expB[(size_t)colIdx * S + jb] = __expf(-C10 * col[permB[i * S + jb]]);
        }
    }
}

// ---------------------------------------------------------------------------
// pair2: one block per (i,j) in perm order (consecutive blocks share columns
// -> L2 locality). Monotone exp => hot loop is pure load/cmp/select/add.
// Finalize fused: per-block atomicAdd into acc (device scope), last block
// (counter) writes out = alpha*acc — removes the reduce dispatch.
// ---------------------------------------------------------------------------
__global__ __launch_bounds__(256) void pair2_kernel(
    const float* __restrict__ expF, const float* __restrict__ expB,
    const int* __restrict__ tlP, const int* __restrict__ fstartA,
    const int* __restrict__ b1endA, float* __restrict__ acc,
    unsigned int* __restrict__ cnt, float* __restrict__ out, int S)
{
    const int bx = blockIdx.x;
    const int i = bx / S;
    const int j = bx - i * S;
    const int tid = threadIdx.x;
    const int tl = tlP[i * S + j];
    const int tk = tl & 0xffff;
    const int lk = tl >> 16;

    float total = 0.f;

    if (lk) {  // forward: suffix [fstart(tk), S) of expF col tk, e > e_k
        const size_t cbase = ((size_t)i * T_CONST + tk) * S;
        const float* __restrict__ cp = expF + cbase;
        const float thr = cp[j];                       // e_k = exp(10 v_k)
        const int lo  = fstartA[i * T_CONST + tk];
        const int loa = (lo + 3) & ~3;
        float sum = 0.f;
        if (tid < loa - lo) { const float e = cp[lo + tid]; sum += (e > thr) ? e : 0.f; }
        for (int p = loa + tid * 4; p < S; p += 1024) {
            const float4 v = *reinterpret_cast<const float4*>(cp + p);
            sum += (v.x > thr) ? v.x : 0.f;
            sum += (v.y > thr) ? v.y : 0.f;
            sum += (v.z > thr) ? v.z : 0.f;
            sum += (v.w > thr) ? v.w : 0.f;
        }
        total += sum * (1.0f / thr);
    }

    if (tk > 0) {  // backward: prefix [0, b1end(cb)) of expB col cb, e > 1/e_k
        const int cb = lk ? tk - 1 : tk;
        const size_t cbase = ((size_t)i * T_CONST + cb) * S;
        const float efk = expF[cbase + j];             // exp(10 v_k) at col cb
        const float thr = 1.0f / efk;
        const float* __restrict__ cp = expB + cbase;
        const int hi  = b1endA[i * T_CONST + cb];
        const int hia = hi & ~3;
        float sum = 0.f;
        for (int p = tid * 4; p < hia; p += 1024) {
            const float4 v = *reinterpret_cast<const float4*>(cp + p);
            sum += (v.x > thr) ? v.x : 0.f;
            sum += (v.y > thr) ? v.y : 0.f;
            sum += (v.z > thr) ? v.z : 0.f;
            sum += (v.w > thr) ? v.w : 0.f;
        }
        if (tid < hi - hia) { const float e = cp[hia + tid]; sum += (e > thr) ? e : 0.f; }
        total += sum * efk;
    }

    for (int off = 32; off > 0; off >>= 1) total += __shfl_down(total, off, 64);
    __shared__ float wsum[4];
    const int lane = tid & 63, wid = tid >> 6;
    if (lane == 0) wsum[wid] = total;
    __syncthreads();
    if (tid == 0) {
        const float bs = wsum[0] + wsum[1] + wsum[2] + wsum[3];
        if (bs != 0.f) atomicAdd(acc, bs);
        __threadfence();
        const unsigned int done = atomicAdd(cnt, 1u);
        if (done == gridDim.x - 1) {
            const float tot = atomicAdd(acc, 0.f);     // atomic read (old value)
            out[0] = ALPHA_C * tot;
        }
    }
}

// ---------------------------------------------------------------------------
// fallback (R1-proven structure): used only if ws_size is too small.
// ---------------------------------------------------------------------------
__global__ __launch_bounds__(256) void pair_kernel(
    const float* __restrict__ cumT, const int* __restrict__ tlA,
    float* __restrict__ partials, int S)
{
    const int bx = blockIdx.x;
    const int i = bx / S;
    const int k = bx - i * S;
    const int base = i * S;
    const int tlk = tlA[base + k];
    const int t_k = tlk & 0xffff;
    const int lab_k = tlk >> 16;
    const bool doF = (lab_k == 1);
    const bool doB = (t_k > 0);
    float sum = 0.f;
    if (doF || doB) {
        const int cb = lab_k ? (t_k > 0 ? t_k - 1 : 0) : t_k;
        const float* __restrict__ colF = cumT + ((size_t)i * T_CONST + t_k) * S;
        const float* __restrict__ colB = cumT + ((size_t)i * T_CONST + cb)  * S;
        const float vf_k = colF[k];
        const float vb_k = colB[k];
        const int* __restrict__ tlp = tlA + base;
        for (int s = threadIdx.x; s < S; s += 256) {
            const int tls = tlp[s];
            const int t_s = tls & 0xffff;
            const int lab_s = tls >> 16;
            if (doF) {
                const float vs = colF[s];
                const bool c = (t_s > t_k) | ((t_s == t_k) & (lab_s == 0));
                if (c & (vs > vf_k)) sum += __expf((vs - vf_k) * C10);
            }
            if (doB) {
                const float vs = colB[s];
                const bool c = (t_s <= cb) & (lab_s == 1);
                if (c & (vb_k > vs)) sum += __expf((vb_k - vs) * C10);
            }
        }
    }
    for (int off = 32; off > 0; off >>= 1) sum += __shfl_down(sum, off, 64);
    __shared__ float wsum[4];
    const int lane = threadIdx.x & 63, wd = threadIdx.x >> 6;
    if (lane == 0) wsum[wd] = sum;
    __syncthreads();
    if (threadIdx.x == 0) partials[bx] = wsum[0] + wsum[1] + wsum[2] + wsum[3];
}

__global__ __launch_bounds__(1024) void reduce_kernel(
    const float* __restrict__ partials, int n, float* __restrict__ out)
{
    float sum = 0.f;
    for (int idx = threadIdx.x; idx < n; idx += 1024) sum += partials[idx];
    for (int off = 32; off > 0; off >>= 1) sum += __shfl_down(sum, off, 64);
    __shared__ float wsum[16];
    const int lane = threadIdx.x & 63, wd = threadIdx.x >> 6;
    if (lane == 0) wsum[wd] = sum;
    __syncthreads();
    if (threadIdx.x == 0) {
        float t = 0.f;
        for (int w = 0; w < 16; ++w) t += wsum[w];
        out[0] = ALPHA_C * t;
    }
}

extern "C" void kernel_launch(void* const* d_in, const int* in_sizes, int n_in,
                              void* d_out, int out_size, void* d_ws, size_t ws_size,
                              hipStream_t stream)
{
    const float* event_out = (const float*)d_in[0];  // (E,S,T) fp32
    const int*   et        = (const int*)d_in[1];    // (S,E) int32
    const int*   labsp     = (const int*)d_in[2];    // (S,E) int32
    const int S = in_sizes[1] / E_CONST;             // 8192

    const size_t colElems = (size_t)E_CONST * T_CONST * S;
    const size_t esElems  = (size_t)E_CONST * S;

    char* p = (char*)d_ws;
    float* cumT   = (float*)p; p += colElems * 4;
    float* expF   = (float*)p; p += colElems * 4;
    float* expB   = (float*)p; p += colElems * 4;
    int*   tlA    = (int*)p;   p += esElems * 4;
    int*   perm   = (int*)p;   p += esElems * 4;
    int*   permB  = (int*)p;   p += esElems * 4;
    int*   tlP    = (int*)p;   p += esElems * 4;
    int*   fstart = (int*)p;   p += E_CONST * T_CONST * 4;
    int*   b1end  = (int*)p;   p += E_CONST * T_CONST * 4;
    float* acc    = (float*)p; p += 64;
    unsigned int* cnt = (unsigned int*)p; p += 64;
    float* partials = (float*)p; p += esElems * 4;   // fallback only
    const size_t needed = (size_t)(p - (char*)d_ws);
    const size_t fallback_needed = colElems * 4 + esElems * 4 * 2 + 128;

    const int nB = E_CONST * S;
    const int prepBlocks = (E_CONST * S + 255) / 256;

    if (ws_size >= needed) {
        hipLaunchKernelGGL(prep_kernel, dim3(prepBlocks), dim3(256), 0, stream,
                           event_out, et, labsp, cumT, tlA, acc, cnt, S);
        hipLaunchKernelGGL(sortmeta_kernel, dim3(E_CONST), dim3(256), 0, stream,
                           et, labsp, perm, permB, tlP, fstart, b1end, S);
        hipLaunchKernelGGL(permute_kernel, dim3(E_CONST * T_CONST, 8), dim3(256), 0, stream,
                           cumT, perm, permB, b1end, expF, expB, S);
        hipLaunchKernelGGL(pair2_kernel, dim3(nB), dim3(256), 0, stream,
                           expF, expB, tlP, fstart, b1end, acc, cnt,
                           (float*)d_out, S);
    } else if (ws_size >= fallback_needed) {
        float* cumT2     = (float*)d_ws;
        int*   tlA2      = (int*)(cumT2 + colElems);
        float* partials2 = (float*)(tlA2 + esElems);
        float* acc2      = (float*)(partials2 + esElems);
        unsigned int* cnt2 = (unsigned int*)(acc2 + 1);
        hipLaunchKernelGGL(prep_kernel, dim3(prepBlocks), dim3(256), 0, stream,
                           event_out, et, labsp, cumT2, tlA2, acc2, cnt2, S);
        hipLaunchKernelGGL(pair_kernel, dim3(nB), dim3(256), 0, stream,
                           cumT2, tlA2, partials2, S);
        hipLaunchKernelGGL(reduce_kernel, dim3(1), dim3(1024), 0, stream,
                           partials2, nB, (float*)d_out);
    }
}

// Round 8
// 151.113 us; speedup vs baseline: 4.3797x; 4.3797x over previous
//
#include <hip/hip_runtime.h>

#define E_CONST 3
#define T_CONST 100
#define C10 10.0f
#define ALPHA_C 0.05f

__device__ inline int waveInclScan(int v, int lane) {
    #pragma unroll
    for (int off = 1; off < 64; off <<= 1) {
        int n = __shfl_up(v, off, 64);
        if (lane >= off) v += n;
    }
    return v;
}

// ---------------------------------------------------------------------------
// combo: blocks [0, prepBlocks) run prep (register cumsum -> transposed
// cumT stores); blocks [prepBlocks, prepBlocks+E) run sortmeta (LDS
// histogram + shuffle scan + counting-sort scatter). The two halves touch
// disjoint data (event_out vs et/labs) and disjoint outputs, so no sync is
// needed — one dispatch overlaps them.
// ---------------------------------------------------------------------------
__global__ __launch_bounds__(256) void combo_kernel(
    const float* __restrict__ event_out, const int* __restrict__ et,
    const int* __restrict__ labs, float* __restrict__ cumT,
    int* __restrict__ perm, int* __restrict__ permB, int* __restrict__ tlP,
    int* __restrict__ fstartA, int* __restrict__ b1endA,
    int prepBlocks, int S)
{
    const int tid = threadIdx.x;

    if ((int)blockIdx.x < prepBlocks) {
        // ---------------- prep half ----------------
        const int gid = blockIdx.x * 256 + tid;       // 0 .. E*S-1
        if (gid >= E_CONST * S) return;
        const int i = gid / S;
        const int s = gid - i * S;
        const float4* __restrict__ row =
            reinterpret_cast<const float4*>(event_out + (size_t)gid * T_CONST);
        float* __restrict__ base = cumT + (size_t)i * T_CONST * S + s;
        float run = 0.f;
        #pragma unroll
        for (int c = 0; c < T_CONST / 4; ++c) {
            const float4 v = row[c];
            const float c0 = run + v.x;
            const float c1 = c0 + v.y;
            const float c2 = c1 + v.z;
            const float c3 = c2 + v.w;
            base[(size_t)(4 * c + 0) * S] = c0;
            base[(size_t)(4 * c + 1) * S] = c1;
            base[(size_t)(4 * c + 2) * S] = c2;
            base[(size_t)(4 * c + 3) * S] = c3;
            run = c3;
        }
        return;
    }

    // ---------------- sortmeta half (one block per event) ----------------
    __shared__ int histK[2 * T_CONST];
    __shared__ int histB[T_CONST];
    __shared__ int cursK[2 * T_CONST];
    __shared__ int cursB[T_CONST];
    __shared__ int wsK[4], wsB[4];
    const int i = (int)blockIdx.x - prepBlocks;
    const int lane = tid & 63, wid = tid >> 6;

    for (int b = tid; b < 2 * T_CONST; b += 256) histK[b] = 0;
    for (int b = tid; b < T_CONST; b += 256) histB[b] = 0;
    __syncthreads();

    for (int s = tid; s < S; s += 256) {
        const int t = et[s * E_CONST + i], lab = labs[s * E_CONST + i];
        atomicAdd(&histK[t * 2 + (1 - lab)], 1);
        if (lab) atomicAdd(&histB[t], 1);
    }
    __syncthreads();

    const int vK = (tid < 2 * T_CONST) ? histK[tid] : 0;
    int inclK = waveInclScan(vK, lane);
    const int vB = (tid < T_CONST) ? histB[tid] : 0;
    int inclB = waveInclScan(vB, lane);
    if (lane == 63) { wsK[wid] = inclK; wsB[wid] = inclB; }
    __syncthreads();
    int offK = 0, offB = 0;
    for (int w = 0; w < wid; ++w) { offK += wsK[w]; offB += wsB[w]; }
    inclK += offK; inclB += offB;
    const int exclK = inclK - vK;
    const int exclB = inclB - vB;

    if (tid < 2 * T_CONST) {
        cursK[tid] = exclK;
        if (tid & 1) fstartA[i * T_CONST + (tid >> 1)] = exclK;  // bin 2t+1
    }
    if (tid < T_CONST) {
        cursB[tid] = exclB;
        b1endA[i * T_CONST + tid] = inclB;
    }
    __syncthreads();

    for (int s = tid; s < S; s += 256) {
        const int t = et[s * E_CONST + i], lab = labs[s * E_CONST + i];
        const int slot = atomicAdd(&cursK[t * 2 + (1 - lab)], 1);
        perm[i * S + slot] = s;
        tlP[i * S + slot]  = (t & 0xffff) | (lab << 16);
        if (lab) {
            const int sb = atomicAdd(&cursB[t], 1);
            permB[i * S + sb] = s;
        }
    }
}

// ---------------------------------------------------------------------------
// permute+exp: expF[i][tau][j] = exp(10*cumT[i][tau][perm[j]]);
//              expB[i][tau][jb] = exp(-10*cumT[i][tau][permB[jb]]), jb < n1.
// Gathers stay within one 32KB column (L1-resident); writes coalesced.
// ---------------------------------------------------------------------------
__global__ __launch_bounds__(256) void permute_kernel(
    const float* __restrict__ cumT, const int* __restrict__ perm,
    const int* __restrict__ permB, const int* __restrict__ b1endA,
    float* __restrict__ expF, float* __restrict__ expB, int S)
{
    const int colIdx = blockIdx.x;            // i*T + tau
    const int i = colIdx / T_CONST;
    const float* __restrict__ col = cumT + (size_t)colIdx * S;
    const int n1 = b1endA[i * T_CONST + T_CONST - 1];
    const int chunk = (2 * S) / 8;
    const int beg = blockIdx.y * chunk;
    const int end = beg + chunk;
    for (int idx = beg + (int)threadIdx.x; idx < end; idx += 256) {
        if (idx < S) {
            expF[(size_t)colIdx * S + idx] = __expf(C10 * col[perm[i * S + idx]]);
        } else {
            const int jb = idx - S;
            if (jb < n1)
                expB[(size_t)colIdx * S + jb] = __expf(-C10 * col[permB[i * S + jb]]);
        }
    }
}

// ---------------------------------------------------------------------------
// pair2 (R5-proven): one block per (i,j) in perm order. Monotone exp =>
// hot loop is pure load/cmp/select/add. Writes partials[bx] — NO global
// same-address atomics (R7 showed 24K same-line atomics cost ~0.5 ms).
// ---------------------------------------------------------------------------
__global__ __launch_bounds__(256) void pair2_kernel(
    const float* __restrict__ expF, const float* __restrict__ expB,
    const int* __restrict__ tlP, const int* __restrict__ fstartA,
    const int* __restrict__ b1endA, float* __restrict__ partials, int S)
{
    const int bx = blockIdx.x;
    const int i = bx / S;
    const int j = bx - i * S;
    const int tid = threadIdx.x;
    const int tl = tlP[i * S + j];
    const int tk = tl & 0xffff;
    const int lk = tl >> 16;

    float total = 0.f;

    if (lk) {  // forward: suffix [fstart(tk), S) of expF col tk, e > e_k
        const size_t cbase = ((size_t)i * T_CONST + tk) * S;
        const float* __restrict__ cp = expF + cbase;
        const float thr = cp[j];                       // e_k = exp(10 v_k)
        const int lo  = fstartA[i * T_CONST + tk];
        const int loa = (lo + 3) & ~3;
        float sum = 0.f;
        if (tid < loa - lo) { const float e = cp[lo + tid]; sum += (e > thr) ? e : 0.f; }
        for (int p = loa + tid * 4; p < S; p += 1024) {
            const float4 v = *reinterpret_cast<const float4*>(cp + p);
            sum += (v.x > thr) ? v.x : 0.f;
            sum += (v.y > thr) ? v.y : 0.f;
            sum += (v.z > thr) ? v.z : 0.f;
            sum += (v.w > thr) ? v.w : 0.f;
        }
        total += sum * (1.0f / thr);
    }

    if (tk > 0) {  // backward: prefix [0, b1end(cb)) of expB col cb, e > 1/e_k
        const int cb = lk ? tk - 1 : tk;
        const size_t cbase = ((size_t)i * T_CONST + cb) * S;
        const float efk = expF[cbase + j];             // exp(10 v_k) at col cb
        const float thr = 1.0f / efk;
        const float* __restrict__ cp = expB + cbase;
        const int hi  = b1endA[i * T_CONST + cb];
        const int hia = hi & ~3;
        float sum = 0.f;
        for (int p = tid * 4; p < hia; p += 1024) {
            const float4 v = *reinterpret_cast<const float4*>(cp + p);
            sum += (v.x > thr) ? v.x : 0.f;
            sum += (v.y > thr) ? v.y : 0.f;
            sum += (v.z > thr) ? v.z : 0.f;
            sum += (v.w > thr) ? v.w : 0.f;
        }
        if (tid < hi - hia) { const float e = cp[hia + tid]; sum += (e > thr) ? e : 0.f; }
        total += sum * efk;
    }

    for (int off = 32; off > 0; off >>= 1) total += __shfl_down(total, off, 64);
    __shared__ float wsum[4];
    const int lane = tid & 63, wid = tid >> 6;
    if (lane == 0) wsum[wid] = total;
    __syncthreads();
    if (tid == 0) partials[bx] = wsum[0] + wsum[1] + wsum[2] + wsum[3];
}

__global__ __launch_bounds__(1024) void reduce_kernel(
    const float* __restrict__ partials, int n, float* __restrict__ out)
{
    float sum = 0.f;
    for (int idx = threadIdx.x; idx < n; idx += 1024) sum += partials[idx];
    for (int off = 32; off > 0; off >>= 1) sum += __shfl_down(sum, off, 64);
    __shared__ float wsum[16];
    const int lane = threadIdx.x & 63, wd = threadIdx.x >> 6;
    if (lane == 0) wsum[wd] = sum;
    __syncthreads();
    if (threadIdx.x == 0) {
        float t = 0.f;
        for (int w = 0; w < 16; ++w) t += wsum[w];
        out[0] = ALPHA_C * t;
    }
}

// ---------------------------------------------------------------------------
// fallback (R1-proven structure): used only if ws_size is too small.
// ---------------------------------------------------------------------------
__global__ __launch_bounds__(64) void prep_fb_kernel(
    const float* __restrict__ event_out, const int* __restrict__ et,
    const int* __restrict__ labs, float* __restrict__ cumT,
    int* __restrict__ tlA, int S)
{
    const int gid = blockIdx.x * 64 + threadIdx.x;
    const int i = gid / S;
    const int s = gid - i * S;
    const float4* __restrict__ row =
        reinterpret_cast<const float4*>(event_out + (size_t)gid * T_CONST);
    float* __restrict__ base = cumT + (size_t)i * T_CONST * S + s;
    float run = 0.f;
    #pragma unroll
    for (int c = 0; c < T_CONST / 4; ++c) {
        const float4 v = row[c];
        const float c0 = run + v.x;
        const float c1 = c0 + v.y;
        const float c2 = c1 + v.z;
        const float c3 = c2 + v.w;
        base[(size_t)(4 * c + 0) * S] = c0;
        base[(size_t)(4 * c + 1) * S] = c1;
        base[(size_t)(4 * c + 2) * S] = c2;
        base[(size_t)(4 * c + 3) * S] = c3;
        run = c3;
    }
    const int t   = et[s * E_CONST + i];
    const int lab = labs[s * E_CONST + i];
    tlA[i * S + s] = (t & 0xffff) | (lab << 16);
}

__global__ __launch_bounds__(256) void pair_fb_kernel(
    const float* __restrict__ cumT, const int* __restrict__ tlA,
    float* __restrict__ partials, int S)
{
    const int bx = blockIdx.x;
    const int i = bx / S;
    const int k = bx - i * S;
    const int base = i * S;
    const int tlk = tlA[base + k];
    const int t_k = tlk & 0xffff;
    const int lab_k = tlk >> 16;
    const bool doF = (lab_k == 1);
    const bool doB = (t_k > 0);
    float sum = 0.f;
    if (doF || doB) {
        const int cb = lab_k ? (t_k > 0 ? t_k - 1 : 0) : t_k;
        const float* __restrict__ colF = cumT + ((size_t)i * T_CONST + t_k) * S;
        const float* __restrict__ colB = cumT + ((size_t)i * T_CONST + cb)  * S;
        const float vf_k = colF[k];
        const float vb_k = colB[k];
        const int* __restrict__ tlp = tlA + base;
        for (int s = threadIdx.x; s < S; s += 256) {
            const int tls = tlp[s];
            const int t_s = tls & 0xffff;
            const int lab_s = tls >> 16;
            if (doF) {
                const float vs = colF[s];
                const bool c = (t_s > t_k) | ((t_s == t_k) & (lab_s == 0));
                if (c & (vs > vf_k)) sum += __expf((vs - vf_k) * C10);
            }
            if (doB) {
                const float vs = colB[s];
                const bool c = (t_s <= cb) & (lab_s == 1);
                if (c & (vb_k > vs)) sum += __expf((vb_k - vs) * C10);
            }
        }
    }
    for (int off = 32; off > 0; off >>= 1) sum += __shfl_down(sum, off, 64);
    __shared__ float wsum[4];
    const int lane = threadIdx.x & 63, wd = threadIdx.x >> 6;
    if (lane == 0) wsum[wd] = sum;
    __syncthreads();
    if (threadIdx.x == 0) partials[bx] = wsum[0] + wsum[1] + wsum[2] + wsum[3];
}

extern "C" void kernel_launch(void* const* d_in, const int* in_sizes, int n_in,
                              void* d_out, int out_size, void* d_ws, size_t ws_size,
                              hipStream_t stream)
{
    const float* event_out = (const float*)d_in[0];  // (E,S,T) fp32
    const int*   et        = (const int*)d_in[1];    // (S,E) int32
    const int*   labsp     = (const int*)d_in[2];    // (S,E) int32
    const int S = in_sizes[1] / E_CONST;             // 8192

    const size_t colElems = (size_t)E_CONST * T_CONST * S;
    const size_t esElems  = (size_t)E_CONST * S;

    char* p = (char*)d_ws;
    float* cumT   = (float*)p; p += colElems * 4;
    float* expF   = (float*)p; p += colElems * 4;
    float* expB   = (float*)p; p += colElems * 4;
    int*   perm   = (int*)p;   p += esElems * 4;
    int*   permB  = (int*)p;   p += esElems * 4;
    int*   tlP    = (int*)p;   p += esElems * 4;
    float* partials = (float*)p; p += esElems * 4;
    int*   fstart = (int*)p;   p += E_CONST * T_CONST * 4;
    int*   b1end  = (int*)p;   p += E_CONST * T_CONST * 4;
    const size_t needed = (size_t)(p - (char*)d_ws);
    const size_t fallback_needed = colElems * 4 + esElems * 4 * 2;

    const int nB = E_CONST * S;
    const int prepBlocks = (E_CONST * S + 255) / 256;

    if (ws_size >= needed) {
        hipLaunchKernelGGL(combo_kernel, dim3(prepBlocks + E_CONST), dim3(256), 0, stream,
                           event_out, et, labsp, cumT, perm, permB, tlP,
                           fstart, b1end, prepBlocks, S);
        hipLaunchKernelGGL(permute_kernel, dim3(E_CONST * T_CONST, 8), dim3(256), 0, stream,
                           cumT, perm, permB, b1end, expF, expB, S);
        hipLaunchKernelGGL(pair2_kernel, dim3(nB), dim3(256), 0, stream,
                           expF, expB, tlP, fstart, b1end, partials, S);
        hipLaunchKernelGGL(reduce_kernel, dim3(1), dim3(1024), 0, stream,
                           partials, nB, (float*)d_out);
    } else if (ws_size >= fallback_needed) {
        float* cumT2     = (float*)d_ws;
        int*   tlA2      = (int*)(cumT2 + colElems);
        float* partials2 = (float*)(tlA2 + esElems);
        hipLaunchKernelGGL(prep_fb_kernel, dim3(E_CONST * S / 64), dim3(64), 0, stream,
                           event_out, et, labsp, cumT2, tlA2, S);
        hipLaunchKernelGGL(pair_fb_kernel, dim3(nB), dim3(256), 0, stream,
                           cumT2, tlA2, partials2, S);
        hipLaunchKernelGGL(reduce_kernel, dim3(1), dim3(1024), 0, stream,
                           partials2, nB, (float*)d_out);
    }
}

// Round 9
// 137.608 us; speedup vs baseline: 4.8095x; 1.0981x over previous
//
#include <hip/hip_runtime.h>

#define E_CONST 3
#define T_CONST 100
#define C10 10.0f
#define ALPHA_C 0.05f

__device__ inline int waveInclScan(int v, int lane) {
    #pragma unroll
    for (int off = 1; off < 64; off <<= 1) {
        int n = __shfl_up(v, off, 64);
        if (lane >= off) v += n;
    }
    return v;
}

// ---------------------------------------------------------------------------
// combo: blocks [0, prepBlocks) run prep (register cumsum -> transposed
// cumT stores); blocks [prepBlocks, prepBlocks+E) run sortmeta (LDS
// histogram + shuffle scan + counting-sort scatter, 4-way unrolled for MLP).
// Disjoint inputs/outputs -> no sync needed; one dispatch overlaps them.
// ---------------------------------------------------------------------------
__global__ __launch_bounds__(256) void combo_kernel(
    const float* __restrict__ event_out, const int* __restrict__ et,
    const int* __restrict__ labs, float* __restrict__ cumT,
    int* __restrict__ perm, int* __restrict__ permB, int* __restrict__ tlP,
    int* __restrict__ fstartA, int* __restrict__ b1endA,
    int prepBlocks, int S)
{
    const int tid = threadIdx.x;

    if ((int)blockIdx.x < prepBlocks) {
        // ---------------- prep half ----------------
        const int gid = blockIdx.x * 256 + tid;       // 0 .. E*S-1
        if (gid >= E_CONST * S) return;
        const int i = gid / S;
        const int s = gid - i * S;
        const float4* __restrict__ row =
            reinterpret_cast<const float4*>(event_out + (size_t)gid * T_CONST);
        float* __restrict__ base = cumT + (size_t)i * T_CONST * S + s;
        float run = 0.f;
        #pragma unroll
        for (int c = 0; c < T_CONST / 4; ++c) {
            const float4 v = row[c];
            const float c0 = run + v.x;
            const float c1 = c0 + v.y;
            const float c2 = c1 + v.z;
            const float c3 = c2 + v.w;
            base[(size_t)(4 * c + 0) * S] = c0;
            base[(size_t)(4 * c + 1) * S] = c1;
            base[(size_t)(4 * c + 2) * S] = c2;
            base[(size_t)(4 * c + 3) * S] = c3;
            run = c3;
        }
        return;
    }

    // ---------------- sortmeta half (one block per event) ----------------
    __shared__ int histK[2 * T_CONST];
    __shared__ int histB[T_CONST];
    __shared__ int cursK[2 * T_CONST];
    __shared__ int cursB[T_CONST];
    __shared__ int wsK[4], wsB[4];
    const int i = (int)blockIdx.x - prepBlocks;
    const int lane = tid & 63, wid = tid >> 6;

    for (int b = tid; b < 2 * T_CONST; b += 256) histK[b] = 0;
    for (int b = tid; b < T_CONST; b += 256) histB[b] = 0;
    __syncthreads();

    // hist pass, 4 independent loads in flight per thread
    for (int s0 = tid; s0 < S; s0 += 1024) {
        const int sB = s0 + 256, sC = s0 + 512, sD = s0 + 768;
        const int tA = et[s0 * E_CONST + i];
        const int lA = labs[s0 * E_CONST + i];
        int tB = 0, lB = 0, tC = 0, lC = 0, tD = 0, lD = 0;
        if (sB < S) { tB = et[sB * E_CONST + i]; lB = labs[sB * E_CONST + i]; }
        if (sC < S) { tC = et[sC * E_CONST + i]; lC = labs[sC * E_CONST + i]; }
        if (sD < S) { tD = et[sD * E_CONST + i]; lD = labs[sD * E_CONST + i]; }
        atomicAdd(&histK[tA * 2 + (1 - lA)], 1); if (lA) atomicAdd(&histB[tA], 1);
        if (sB < S) { atomicAdd(&histK[tB * 2 + (1 - lB)], 1); if (lB) atomicAdd(&histB[tB], 1); }
        if (sC < S) { atomicAdd(&histK[tC * 2 + (1 - lC)], 1); if (lC) atomicAdd(&histB[tC], 1); }
        if (sD < S) { atomicAdd(&histK[tD * 2 + (1 - lD)], 1); if (lD) atomicAdd(&histB[tD], 1); }
    }
    __syncthreads();

    const int vK = (tid < 2 * T_CONST) ? histK[tid] : 0;
    int inclK = waveInclScan(vK, lane);
    const int vB = (tid < T_CONST) ? histB[tid] : 0;
    int inclB = waveInclScan(vB, lane);
    if (lane == 63) { wsK[wid] = inclK; wsB[wid] = inclB; }
    __syncthreads();
    int offK = 0, offB = 0;
    for (int w = 0; w < wid; ++w) { offK += wsK[w]; offB += wsB[w]; }
    inclK += offK; inclB += offB;
    const int exclK = inclK - vK;
    const int exclB = inclB - vB;

    if (tid < 2 * T_CONST) {
        cursK[tid] = exclK;
        if (tid & 1) fstartA[i * T_CONST + (tid >> 1)] = exclK;  // bin 2t+1
    }
    if (tid < T_CONST) {
        cursB[tid] = exclB;
        b1endA[i * T_CONST + tid] = inclB;
    }
    __syncthreads();

    // scatter pass, 4 independent loads in flight per thread
    for (int s0 = tid; s0 < S; s0 += 1024) {
        const int sB = s0 + 256, sC = s0 + 512, sD = s0 + 768;
        const int tA = et[s0 * E_CONST + i];
        const int lA = labs[s0 * E_CONST + i];
        int tB = 0, lB = 0, tC = 0, lC = 0, tD = 0, lD = 0;
        if (sB < S) { tB = et[sB * E_CONST + i]; lB = labs[sB * E_CONST + i]; }
        if (sC < S) { tC = et[sC * E_CONST + i]; lC = labs[sC * E_CONST + i]; }
        if (sD < S) { tD = et[sD * E_CONST + i]; lD = labs[sD * E_CONST + i]; }

        int slot = atomicAdd(&cursK[tA * 2 + (1 - lA)], 1);
        perm[i * S + slot] = s0;
        tlP[i * S + slot]  = (tA & 0xffff) | (lA << 16);
        if (lA) { const int sb = atomicAdd(&cursB[tA], 1); permB[i * S + sb] = s0; }
        if (sB < S) {
            slot = atomicAdd(&cursK[tB * 2 + (1 - lB)], 1);
            perm[i * S + slot] = sB;
            tlP[i * S + slot]  = (tB & 0xffff) | (lB << 16);
            if (lB) { const int sb = atomicAdd(&cursB[tB], 1); permB[i * S + sb] = sB; }
        }
        if (sC < S) {
            slot = atomicAdd(&cursK[tC * 2 + (1 - lC)], 1);
            perm[i * S + slot] = sC;
            tlP[i * S + slot]  = (tC & 0xffff) | (lC << 16);
            if (lC) { const int sb = atomicAdd(&cursB[tC], 1); permB[i * S + sb] = sC; }
        }
        if (sD < S) {
            slot = atomicAdd(&cursK[tD * 2 + (1 - lD)], 1);
            perm[i * S + slot] = sD;
            tlP[i * S + slot]  = (tD & 0xffff) | (lD << 16);
            if (lD) { const int sb = atomicAdd(&cursB[tD], 1); permB[i * S + sb] = sD; }
        }
    }
}

// ---------------------------------------------------------------------------
// permute+exp: expF[i][tau][j] = exp(10*cumT[i][tau][perm[j]]);
//              expB[i][tau][jb] = exp(-10*cumT[i][tau][permB[jb]]), jb < n1.
// y-split 32 (9600 blocks, 2 gathers/thread) so gather latency is hidden by
// TLP rather than per-thread ILP.
// ---------------------------------------------------------------------------
__global__ __launch_bounds__(256) void permute_kernel(
    const float* __restrict__ cumT, const int* __restrict__ perm,
    const int* __restrict__ permB, const int* __restrict__ b1endA,
    float* __restrict__ expF, float* __restrict__ expB, int S)
{
    const int colIdx = blockIdx.x;            // i*T + tau
    const int i = colIdx / T_CONST;
    const float* __restrict__ col = cumT + (size_t)colIdx * S;
    const int n1 = b1endA[i * T_CONST + T_CONST - 1];
    const int chunk = (2 * S) / 32;
    const int beg = blockIdx.y * chunk;
    const int end = beg + chunk;
    for (int idx = beg + (int)threadIdx.x; idx < end; idx += 256) {
        if (idx < S) {
            expF[(size_t)colIdx * S + idx] = __expf(C10 * col[perm[i * S + idx]]);
        } else {
            const int jb = idx - S;
            if (jb < n1)
                expB[(size_t)colIdx * S + jb] = __expf(-C10 * col[permB[i * S + jb]]);
        }
    }
}

// ---------------------------------------------------------------------------
// pair2 (proven): one block per (i,j) in perm order. Monotone exp => hot loop
// is pure load/cmp/select/add. Writes partials[bx] — no global atomics.
// ---------------------------------------------------------------------------
__global__ __launch_bounds__(256) void pair2_kernel(
    const float* __restrict__ expF, const float* __restrict__ expB,
    const int* __restrict__ tlP, const int* __restrict__ fstartA,
    const int* __restrict__ b1endA, float* __restrict__ partials, int S)
{
    const int bx = blockIdx.x;
    const int i = bx / S;
    const int j = bx - i * S;
    const int tid = threadIdx.x;
    const int tl = tlP[i * S + j];
    const int tk = tl & 0xffff;
    const int lk = tl >> 16;

    float total = 0.f;

    if (lk) {  // forward: suffix [fstart(tk), S) of expF col tk, e > e_k
        const size_t cbase = ((size_t)i * T_CONST + tk) * S;
        const float* __restrict__ cp = expF + cbase;
        const float thr = cp[j];                       // e_k = exp(10 v_k)
        const int lo  = fstartA[i * T_CONST + tk];
        const int loa = (lo + 3) & ~3;
        float sum = 0.f;
        if (tid < loa - lo) { const float e = cp[lo + tid]; sum += (e > thr) ? e : 0.f; }
        for (int p = loa + tid * 4; p < S; p += 1024) {
            const float4 v = *reinterpret_cast<const float4*>(cp + p);
            sum += (v.x > thr) ? v.x : 0.f;
            sum += (v.y > thr) ? v.y : 0.f;
            sum += (v.z > thr) ? v.z : 0.f;
            sum += (v.w > thr) ? v.w : 0.f;
        }
        total += sum * (1.0f / thr);
    }

    if (tk > 0) {  // backward: prefix [0, b1end(cb)) of expB col cb, e > 1/e_k
        const int cb = lk ? tk - 1 : tk;
        const size_t cbase = ((size_t)i * T_CONST + cb) * S;
        const float efk = expF[cbase + j];             // exp(10 v_k) at col cb
        const float thr = 1.0f / efk;
        const float* __restrict__ cp = expB + cbase;
        const int hi  = b1endA[i * T_CONST + cb];
        const int hia = hi & ~3;
        float sum = 0.f;
        for (int p = tid * 4; p < hia; p += 1024) {
            const float4 v = *reinterpret_cast<const float4*>(cp + p);
            sum += (v.x > thr) ? v.x : 0.f;
            sum += (v.y > thr) ? v.y : 0.f;
            sum += (v.z > thr) ? v.z : 0.f;
            sum += (v.w > thr) ? v.w : 0.f;
        }
        if (tid < hi - hia) { const float e = cp[hia + tid]; sum += (e > thr) ? e : 0.f; }
        total += sum * efk;
    }

    for (int off = 32; off > 0; off >>= 1) total += __shfl_down(total, off, 64);
    __shared__ float wsum[4];
    const int lane = tid & 63, wid = tid >> 6;
    if (lane == 0) wsum[wid] = total;
    __syncthreads();
    if (tid == 0) partials[bx] = wsum[0] + wsum[1] + wsum[2] + wsum[3];
}

// ---------------------------------------------------------------------------
// reduce: float4 loads, 4 independent accumulators for MLP. n % 4096 == 0
// not required (tail-safe via scalar loop).
// ---------------------------------------------------------------------------
__global__ __launch_bounds__(1024) void reduce_kernel(
    const float* __restrict__ partials, int n, float* __restrict__ out)
{
    const int tid = threadIdx.x;
    float s0 = 0.f, s1 = 0.f, s2 = 0.f, s3 = 0.f;
    const int n4 = n & ~3;
    for (int idx = tid * 4; idx < n4; idx += 4096) {
        const float4 v = *reinterpret_cast<const float4*>(partials + idx);
        s0 += v.x; s1 += v.y; s2 += v.z; s3 += v.w;
    }
    for (int idx = n4 + tid; idx < n; idx += 1024) s0 += partials[idx];
    float sum = (s0 + s1) + (s2 + s3);
    for (int off = 32; off > 0; off >>= 1) sum += __shfl_down(sum, off, 64);
    __shared__ float wsum[16];
    const int lane = tid & 63, wd = tid >> 6;
    if (lane == 0) wsum[wd] = sum;
    __syncthreads();
    if (tid == 0) {
        float t = 0.f;
        for (int w = 0; w < 16; ++w) t += wsum[w];
        out[0] = ALPHA_C * t;
    }
}

// ---------------------------------------------------------------------------
// fallback (R1-proven structure): used only if ws_size is too small.
// ---------------------------------------------------------------------------
__global__ __launch_bounds__(64) void prep_fb_kernel(
    const float* __restrict__ event_out, const int* __restrict__ et,
    const int* __restrict__ labs, float* __restrict__ cumT,
    int* __restrict__ tlA, int S)
{
    const int gid = blockIdx.x * 64 + threadIdx.x;
    const int i = gid / S;
    const int s = gid - i * S;
    const float4* __restrict__ row =
        reinterpret_cast<const float4*>(event_out + (size_t)gid * T_CONST);
    float* __restrict__ base = cumT + (size_t)i * T_CONST * S + s;
    float run = 0.f;
    #pragma unroll
    for (int c = 0; c < T_CONST / 4; ++c) {
        const float4 v = row[c];
        const float c0 = run + v.x;
        const float c1 = c0 + v.y;
        const float c2 = c1 + v.z;
        const float c3 = c2 + v.w;
        base[(size_t)(4 * c + 0) * S] = c0;
        base[(size_t)(4 * c + 1) * S] = c1;
        base[(size_t)(4 * c + 2) * S] = c2;
        base[(size_t)(4 * c + 3) * S] = c3;
        run = c3;
    }
    const int t   = et[s * E_CONST + i];
    const int lab = labs[s * E_CONST + i];
    tlA[i * S + s] = (t & 0xffff) | (lab << 16);
}

__global__ __launch_bounds__(256) void pair_fb_kernel(
    const float* __restrict__ cumT, const int* __restrict__ tlA,
    float* __restrict__ partials, int S)
{
    const int bx = blockIdx.x;
    const int i = bx / S;
    const int k = bx - i * S;
    const int base = i * S;
    const int tlk = tlA[base + k];
    const int t_k = tlk & 0xffff;
    const int lab_k = tlk >> 16;
    const bool doF = (lab_k == 1);
    const bool doB = (t_k > 0);
    float sum = 0.f;
    if (doF || doB) {
        const int cb = lab_k ? (t_k > 0 ? t_k - 1 : 0) : t_k;
        const float* __restrict__ colF = cumT + ((size_t)i * T_CONST + t_k) * S;
        const float* __restrict__ colB = cumT + ((size_t)i * T_CONST + cb)  * S;
        const float vf_k = colF[k];
        const float vb_k = colB[k];
        const int* __restrict__ tlp = tlA + base;
        for (int s = threadIdx.x; s < S; s += 256) {
            const int tls = tlp[s];
            const int t_s = tls & 0xffff;
            const int lab_s = tls >> 16;
            if (doF) {
                const float vs = colF[s];
                const bool c = (t_s > t_k) | ((t_s == t_k) & (lab_s == 0));
                if (c & (vs > vf_k)) sum += __expf((vs - vf_k) * C10);
            }
            if (doB) {
                const float vs = colB[s];
                const bool c = (t_s <= cb) & (lab_s == 1);
                if (c & (vb_k > vs)) sum += __expf((vb_k - vs) * C10);
            }
        }
    }
    for (int off = 32; off > 0; off >>= 1) sum += __shfl_down(sum, off, 64);
    __shared__ float wsum[4];
    const int lane = threadIdx.x & 63, wd = threadIdx.x >> 6;
    if (lane == 0) wsum[wd] = sum;
    __syncthreads();
    if (threadIdx.x == 0) partials[bx] = wsum[0] + wsum[1] + wsum[2] + wsum[3];
}

extern "C" void kernel_launch(void* const* d_in, const int* in_sizes, int n_in,
                              void* d_out, int out_size, void* d_ws, size_t ws_size,
                              hipStream_t stream)
{
    const float* event_out = (const float*)d_in[0];  // (E,S,T) fp32
    const int*   et        = (const int*)d_in[1];    // (S,E) int32
    const int*   labsp     = (const int*)d_in[2];    // (S,E) int32
    const int S = in_sizes[1] / E_CONST;             // 8192

    const size_t colElems = (size_t)E_CONST * T_CONST * S;
    const size_t esElems  = (size_t)E_CONST * S;

    char* p = (char*)d_ws;
    float* cumT   = (float*)p; p += colElems * 4;
    float* expF   = (float*)p; p += colElems * 4;
    float* expB   = (float*)p; p += colElems * 4;
    int*   perm   = (int*)p;   p += esElems * 4;
    int*   permB  = (int*)p;   p += esElems * 4;
    int*   tlP    = (int*)p;   p += esElems * 4;
    float* partials = (float*)p; p += esElems * 4;
    int*   fstart = (int*)p;   p += E_CONST * T_CONST * 4;
    int*   b1end  = (int*)p;   p += E_CONST * T_CONST * 4;
    const size_t needed = (size_t)(p - (char*)d_ws);
    const size_t fallback_needed = colElems * 4 + esElems * 4 * 2;

    const int nB = E_CONST * S;
    const int prepBlocks = (E_CONST * S + 255) / 256;

    if (ws_size >= needed) {
        hipLaunchKernelGGL(combo_kernel, dim3(prepBlocks + E_CONST), dim3(256), 0, stream,
                           event_out, et, labsp, cumT, perm, permB, tlP,
                           fstart, b1end, prepBlocks, S);
        hipLaunchKernelGGL(permute_kernel, dim3(E_CONST * T_CONST, 32), dim3(256), 0, stream,
                           cumT, perm, permB, b1end, expF, expB, S);
        hipLaunchKernelGGL(pair2_kernel, dim3(nB), dim3(256), 0, stream,
                           expF, expB, tlP, fstart, b1end, partials, S);
        hipLaunchKernelGGL(reduce_kernel, dim3(1), dim3(1024), 0, stream,
                           partials, nB, (float*)d_out);
    } else if (ws_size >= fallback_needed) {
        float* cumT2     = (float*)d_ws;
        int*   tlA2      = (int*)(cumT2 + colElems);
        float* partials2 = (float*)(tlA2 + esElems);
        hipLaunchKernelGGL(prep_fb_kernel, dim3(E_CONST * S / 64), dim3(64), 0, stream,
                           event_out, et, labsp, cumT2, tlA2, S);
        hipLaunchKernelGGL(pair_fb_kernel, dim3(nB), dim3(256), 0, stream,
                           cumT2, tlA2, partials2, S);
        hipLaunchKernelGGL(reduce_kernel, dim3(1), dim3(1024), 0, stream,
                           partials2, nB, (float*)d_out);
    }
}